// Round 21
// baseline (257.641 us; speedup 1.0000x reference)
//
#include <hip/hip_runtime.h>
#include <hip/hip_fp16.h>
#include <math.h>

#define HEADS 4
#define CH 256
#define HC 1024
#define NSLICE 4
#define NEG_SLOPE 0.2f
#define MAXS 320   // staged CSR slots per block (4 nodes)
#define ASCALE (1.0f / 1024.0f)  // alpha scale: keeps exp() in fp16 range; exact pow2

typedef _Float16 f16x8 __attribute__((ext_vector_type(8)));
typedef _Float16 f16x4 __attribute__((ext_vector_type(4)));
typedef __attribute__((ext_vector_type(4))) float f32x4;

static inline int cdiv(int a, int b) { return (a + b - 1) / b; }

__device__ __forceinline__ __half2 u2h2(unsigned u) {
  union {
    unsigned u;
    __half2 h;
  } x;
  x.u = u;
  return x.h;
}
__device__ __forceinline__ unsigned h22u(__half2 h) {
  union {
    __half2 h;
    unsigned u;
  } x;
  x.h = h;
  return x.u;
}
__device__ __forceinline__ void gload_lds16(const void* g, void* l) {
  __builtin_amdgcn_global_load_lds((const __attribute__((address_space(1))) void*)g,
                                   (__attribute__((address_space(3))) void*)l, 16, 0, 0);
}

// ---------------- CSR build ----------------
__global__ void k_count(const int* __restrict__ ei, int E, int ET, int* __restrict__ cnt) {
  int e = blockIdx.x * blockDim.x + threadIdx.x;
  if (e >= ET) return;
  int d = (e < E) ? ei[E + e] : (e - E);
  atomicAdd(&cnt[d], 1);
}

__global__ __launch_bounds__(1024) void k_scan(const int* __restrict__ counts,
                                               int* __restrict__ offsets, int n) {
  __shared__ int wsum[16];
  __shared__ int carry_s;
  int lane = threadIdx.x & 63, wv = threadIdx.x >> 6;
  if (threadIdx.x == 0) carry_s = 0;
  __syncthreads();
  for (int base = 0; base < n; base += 1024) {
    int i = base + threadIdx.x;
    int orig = (i < n) ? counts[i] : 0;
    int v = orig;
#pragma unroll
    for (int off = 1; off < 64; off <<= 1) {
      int t = __shfl_up(v, off);
      if (lane >= off) v += t;
    }
    if (lane == 63) wsum[wv] = v;
    __syncthreads();
    int carry = carry_s;
    int wpre = 0;
#pragma unroll
    for (int w = 0; w < 16; w++) wpre += (w < wv) ? wsum[w] : 0;
    int incl = v + wpre;
    if (i < n) offsets[i] = carry + incl - orig;
    __syncthreads();
    if (threadIdx.x == 1023) carry_s = carry + incl;
    __syncthreads();
  }
  if (threadIdx.x == 0) offsets[n] = carry_s;
}

__global__ void k_fill(const int* __restrict__ ei, int E, int ET,
                       const int* __restrict__ offsets, int* __restrict__ cursor,
                       int2* __restrict__ esd) {
  int e = blockIdx.x * blockDim.x + threadIdx.x;
  if (e >= ET) return;
  int s = (e < E) ? ei[e] : (e - E);
  int d = (e < E) ? ei[E + e] : (e - E);
  int pos = offsets[d] + atomicAdd(&cursor[d], 1);
  esd[pos] = make_int2(s, d);
}

// ---------------- W transpose + cast to fp16 ----------------
__global__ __launch_bounds__(256) void k_transpose_w(const float* __restrict__ W,
                                                     _Float16* __restrict__ Wt, int K) {
  __shared__ float tile[32][33];
  int tx = threadIdx.x & 31, ty = threadIdx.x >> 5;
  int k0 = blockIdx.x * 32, n0 = blockIdx.y * 32;
#pragma unroll
  for (int r = ty; r < 32; r += 8) tile[r][tx] = W[(size_t)(k0 + r) * HC + n0 + tx];
  __syncthreads();
#pragma unroll
  for (int r = ty; r < 32; r += 8)
    Wt[(size_t)(n0 + r) * K + k0 + tx] = (_Float16)tile[tx][r];
}

// ---------------- cast fp32 -> fp16 ----------------
__global__ void k_cast_f16(const float* __restrict__ in, _Float16* __restrict__ out, int n) {
  int i = (blockIdx.x * blockDim.x + threadIdx.x) * 8;
  if (i >= n) return;
  float4 a = *(const float4*)&in[i];
  float4 b = *(const float4*)&in[i + 4];
  f16x8 o;
  o[0] = (_Float16)a.x;
  o[1] = (_Float16)a.y;
  o[2] = (_Float16)a.z;
  o[3] = (_Float16)a.w;
  o[4] = (_Float16)b.x;
  o[5] = (_Float16)b.y;
  o[6] = (_Float16)b.z;
  o[7] = (_Float16)b.w;
  *(f16x8*)&out[i] = o;
}

// ---------------- fp16 MFMA GEMM + fused logits epilogue ----------------
// Writes slice-major hsl[c][n][256] (NSLICE=4) AND accumulates es/ed row-dots
// from the fp32 accumulators (head uniform per 128-col block since 128|256):
// per (i,r) row: partial = sum_j acc[i][j][r]*a[col]; reduce over l15 (4 shfl);
// lane l15==0 atomicAdds (2 writers per address: the two col-halves of a head).
__global__ __launch_bounds__(256) void k_gemm_mfma(const _Float16* __restrict__ A,
                                                   const _Float16* __restrict__ Bt,
                                                   _Float16* __restrict__ hsl,
                                                   const float* __restrict__ as_,
                                                   const float* __restrict__ ad_,
                                                   float* __restrict__ es,
                                                   float* __restrict__ ed, int M, int K) {
  __shared__ _Float16 sA[2][128 * 32];
  __shared__ _Float16 sB[2][128 * 32];
  int t = threadIdx.x;
  int lane = t & 63, wv = t >> 6;
  int wr = wv >> 1, wc = wv & 1;
  int row0 = blockIdx.x * 128, col0 = blockIdx.y * 128;
  int l15 = lane & 15, l4 = lane >> 4;

  f32x4 acc[4][4] = {};

  auto stage = [&](_Float16* sdst, const _Float16* g, int grow0, int rowmax, int k0) {
#pragma unroll
    for (int q = 0; q < 2; ++q) {
      int r = grow0 + q * 64 + (t >> 2);
      if (r > rowmax) r = rowmax;
      const _Float16* gp = g + (size_t)r * K + k0 + (t & 3) * 8;
      gload_lds16(gp, sdst + q * 2048 + t * 8);
    }
  };

  int KT = K / 32;
  stage(sA[0], A, row0, M - 1, 0);
  stage(sB[0], Bt, col0, HC - 1, 0);
  int cur = 0;
  for (int kt = 0; kt < KT; ++kt) {
    __syncthreads();
    if (kt + 1 < KT) {
      stage(sA[cur ^ 1], A, row0, M - 1, (kt + 1) * 32);
      stage(sB[cur ^ 1], Bt, col0, HC - 1, (kt + 1) * 32);
    }
    f16x8 af[4], bfr[4];
#pragma unroll
    for (int i = 0; i < 4; i++)
      af[i] = *(f16x8*)&sA[cur][(wr * 64 + i * 16 + l15) * 32 + l4 * 8];
#pragma unroll
    for (int j = 0; j < 4; j++)
      bfr[j] = *(f16x8*)&sB[cur][(wc * 64 + j * 16 + l15) * 32 + l4 * 8];
#pragma unroll
    for (int i = 0; i < 4; i++)
#pragma unroll
      for (int j = 0; j < 4; j++)
        acc[i][j] = __builtin_amdgcn_mfma_f32_16x16x32_f16(af[i], bfr[j], acc[i][j], 0, 0, 0);
    cur ^= 1;
  }
  // ---- C write (slice-major fp16) ----
#pragma unroll
  for (int i = 0; i < 4; i++) {
#pragma unroll
    for (int j = 0; j < 4; j++) {
      int col = col0 + wc * 64 + j * 16 + l15;
      int head = col >> 8;
      int c = (col >> 6) & 3;
      int jj = col & 63;
      size_t sbase = ((size_t)c * M) * 256 + head * 64 + jj;
#pragma unroll
      for (int r = 0; r < 4; r++) {
        int row = row0 + wr * 64 + i * 16 + l4 * 4 + r;
        if (row < M) hsl[sbase + (size_t)row * 256] = (_Float16)acc[i][j][r];
      }
    }
  }
  // ---- fused logits: row-dots from fp32 accumulators ----
  {
    int head = col0 >> 8;
    int cb = head * 256 + (col0 & 255) + wc * 64 + l15;
    float asv[4], adv[4];
#pragma unroll
    for (int j = 0; j < 4; j++) {
      asv[j] = as_[cb + j * 16];
      adv[j] = ad_[cb + j * 16];
    }
#pragma unroll
    for (int i = 0; i < 4; i++) {
#pragma unroll
      for (int r = 0; r < 4; r++) {
        float dsp = acc[i][0][r] * asv[0] + acc[i][1][r] * asv[1] + acc[i][2][r] * asv[2] +
                    acc[i][3][r] * asv[3];
        float ddp = acc[i][0][r] * adv[0] + acc[i][1][r] * adv[1] + acc[i][2][r] * adv[2] +
                    acc[i][3][r] * adv[3];
#pragma unroll
        for (int off = 1; off < 16; off <<= 1) {
          dsp += __shfl_xor(dsp, off);
          ddp += __shfl_xor(ddp, off);
        }
        int row = row0 + wr * 64 + i * 16 + l4 * 4 + r;
        if (l15 == 0 && row < M) {
          atomicAdd(&es[row * 4 + head], dsp);
          atomicAdd(&ed[row * 4 + head], ddp);
        }
      }
    }
  }
}

// ---------------- XCD-sliced aggregation (R18-proven), fused edge-exp staging --------
__global__ __launch_bounds__(256) void k_aggregate(const _Float16* __restrict__ hsl,
                                                   const float4* __restrict__ es4,
                                                   const float4* __restrict__ ed4,
                                                   const float* __restrict__ es,
                                                   const float* __restrict__ ed,
                                                   const int* __restrict__ offsets,
                                                   const int2* __restrict__ esd,
                                                   const float* __restrict__ bias,
                                                   float* __restrict__ xout,
                                                   _Float16* __restrict__ xout_h, int N) {
  __shared__ uint4 s_ap[MAXS];
  __shared__ int s_src[MAXS];
  int c = blockIdx.x & 3;
  int nb = (blockIdx.x >> 2) * 4;
  int base = offsets[nb];
  int nend = (nb + 4 < N) ? nb + 4 : N;
  int total = offsets[nend] - base;
  int cap = total < MAXS ? total : MAXS;
  for (int idx = threadIdx.x; idx < cap; idx += 256) {
    int2 sd = esd[base + idx];
    float4 a = es4[sd.x], b = ed4[sd.y];
    float v0 = a.x + b.x, v1 = a.y + b.y, v2 = a.z + b.z, v3 = a.w + b.w;
    v0 = v0 > 0.f ? v0 : NEG_SLOPE * v0;
    v1 = v1 > 0.f ? v1 : NEG_SLOPE * v1;
    v2 = v2 > 0.f ? v2 : NEG_SLOPE * v2;
    v3 = v3 > 0.f ? v3 : NEG_SLOPE * v3;
    uint4 ap;
    ap.x = h22u(__float2half2_rn(__expf(v0) * ASCALE));
    ap.y = h22u(__float2half2_rn(__expf(v1) * ASCALE));
    ap.z = h22u(__float2half2_rn(__expf(v2) * ASCALE));
    ap.w = h22u(__float2half2_rn(__expf(v3) * ASCALE));
    s_ap[idx] = ap;
    s_src[idx] = sd.x;
  }
  __syncthreads();
  int n = nb + (threadIdx.x >> 6);
  if (n >= N) return;
  int lane = threadIdx.x & 63;
  int g = lane >> 5;
  int q = lane & 31;
  int hq = q >> 3;
  const _Float16* sl = hsl + (size_t)c * N * 256;
  const __half2* aph = (const __half2*)s_ap;
  __half2 z2 = __float2half2_rn(0.f);
  __half2 acc2[4] = {z2, z2, z2, z2};
  __half2 sum2 = z2;
  int k0 = offsets[n], k1 = offsets[n + 1];
  int r = k0 - base + g;
  int rend = k1 - base;
  if (total <= MAXS) {
    for (; r + 2 < rend; r += 4) {
      int sA = s_src[r], sB = s_src[r + 2];
      __half2 aA = aph[r * 4 + hq];
      __half2 aB = aph[(r + 2) * 4 + hq];
      uint4 hA = *(const uint4*)&sl[(size_t)sA * 256 + q * 8];
      uint4 hB = *(const uint4*)&sl[(size_t)sB * 256 + q * 8];
      sum2 = __hadd2(sum2, __hadd2(aA, aB));
      acc2[0] = __hfma2(aA, u2h2(hA.x), acc2[0]);
      acc2[1] = __hfma2(aA, u2h2(hA.y), acc2[1]);
      acc2[2] = __hfma2(aA, u2h2(hA.z), acc2[2]);
      acc2[3] = __hfma2(aA, u2h2(hA.w), acc2[3]);
      acc2[0] = __hfma2(aB, u2h2(hB.x), acc2[0]);
      acc2[1] = __hfma2(aB, u2h2(hB.y), acc2[1]);
      acc2[2] = __hfma2(aB, u2h2(hB.z), acc2[2]);
      acc2[3] = __hfma2(aB, u2h2(hB.w), acc2[3]);
    }
    if (r < rend) {
      int sA = s_src[r];
      __half2 aA = aph[r * 4 + hq];
      uint4 hA = *(const uint4*)&sl[(size_t)sA * 256 + q * 8];
      sum2 = __hadd2(sum2, aA);
      acc2[0] = __hfma2(aA, u2h2(hA.x), acc2[0]);
      acc2[1] = __hfma2(aA, u2h2(hA.y), acc2[1]);
      acc2[2] = __hfma2(aA, u2h2(hA.z), acc2[2]);
      acc2[3] = __hfma2(aA, u2h2(hA.w), acc2[3]);
    }
  } else {
    for (; r < rend; r += 2) {
      int2 sd = esd[base + r];
      float v = es[sd.x * 4 + hq] + ed[sd.y * 4 + hq];
      v = v > 0.f ? v : NEG_SLOPE * v;
      __half2 aA = __float2half2_rn(__expf(v) * ASCALE);
      uint4 hA = *(const uint4*)&sl[(size_t)sd.x * 256 + q * 8];
      sum2 = __hadd2(sum2, aA);
      acc2[0] = __hfma2(aA, u2h2(hA.x), acc2[0]);
      acc2[1] = __hfma2(aA, u2h2(hA.y), acc2[1]);
      acc2[2] = __hfma2(aA, u2h2(hA.z), acc2[2]);
      acc2[3] = __hfma2(aA, u2h2(hA.w), acc2[3]);
    }
  }
  float sa = __low2float(sum2);
  sa += __shfl_xor(sa, 32);
  float ia = 0.25f / (sa + 1e-20f);
  float acc[8];
#pragma unroll
  for (int j = 0; j < 4; j++) {
    acc[2 * j] = __low2float(acc2[j]) * ia;
    acc[2 * j + 1] = __high2float(acc2[j]) * ia;
  }
#pragma unroll
  for (int j = 0; j < 8; j++) {
    float v = acc[j];
    v += __shfl_xor(v, 8);
    v += __shfl_xor(v, 16);
    v += __shfl_xor(v, 32);
    acc[j] = v;
  }
  if (lane < 8) {
    int oc = c * 64 + lane * 8;
    if (xout) {
      float4 o0 = make_float4(acc[0] + bias[oc + 0], acc[1] + bias[oc + 1],
                              acc[2] + bias[oc + 2], acc[3] + bias[oc + 3]);
      float4 o1 = make_float4(acc[4] + bias[oc + 4], acc[5] + bias[oc + 5],
                              acc[6] + bias[oc + 6], acc[7] + bias[oc + 7]);
      *(float4*)&xout[(size_t)n * CH + oc] = o0;
      *(float4*)&xout[(size_t)n * CH + oc + 4] = o1;
    }
    if (xout_h) {
      f16x8 o;
#pragma unroll
      for (int j = 0; j < 8; j++) o[j] = (_Float16)(acc[j] + bias[oc + j]);
      *(f16x8*)&xout_h[(size_t)n * CH + oc] = o;
    }
  }
}

extern "C" void kernel_launch(void* const* d_in, const int* in_sizes, int n_in,
                              void* d_out, int out_size, void* d_ws, size_t ws_size,
                              hipStream_t stream) {
  const float* x = (const float*)d_in[0];
  const int* ei = (const int*)d_in[1];
  const float* W[3] = {(const float*)d_in[2], (const float*)d_in[6], (const float*)d_in[10]};
  const float* AS[3] = {(const float*)d_in[3], (const float*)d_in[7], (const float*)d_in[11]};
  const float* AD[3] = {(const float*)d_in[4], (const float*)d_in[8], (const float*)d_in[12]};
  const float* BI[3] = {(const float*)d_in[5], (const float*)d_in[9], (const float*)d_in[13]};
  const int N = in_sizes[0] / 512;
  const int E = in_sizes[1] / 2;
  const int ET = E + N;
  const int Kd[3] = {512, 256, 256};

  char* p = (char*)d_ws;
  auto alloc = [&](size_t bytes) {
    char* r = p;
    p += (bytes + 255) & ~(size_t)255;
    return (void*)r;
  };
  _Float16* hsl = (_Float16*)alloc((size_t)NSLICE * N * 256 * 2);
  _Float16* axh = (_Float16*)alloc((size_t)N * 512 * 2);
  _Float16* acth = (_Float16*)alloc((size_t)N * CH * 2);
  _Float16* Wt[3];
  for (int i = 0; i < 3; i++) Wt[i] = (_Float16*)alloc((size_t)HC * Kd[i] * 2);
  float* es = (float*)alloc((size_t)N * HEADS * 4);  // N*16 B, 256-aligned multiple
  float* ed = (float*)alloc((size_t)N * HEADS * 4);  // contiguous after es
  int* offsets = (int*)alloc((size_t)(N + 1) * 4);
  int* cursor = (int*)alloc((size_t)N * 4);
  int2* esd = (int2*)alloc((size_t)ET * 8);

  // ---- CSR build (shared by all 3 layers) ----
  hipMemsetAsync(cursor, 0, (size_t)N * 4, stream);
  k_count<<<cdiv(ET, 256), 256, 0, stream>>>(ei, E, ET, cursor);
  k_scan<<<1, 1024, 0, stream>>>(cursor, offsets, N);
  hipMemsetAsync(cursor, 0, (size_t)N * 4, stream);
  k_fill<<<cdiv(ET, 256), 256, 0, stream>>>(ei, E, ET, offsets, cursor, esd);

  // ---- weight transpose+cast, input cast ----
  for (int i = 0; i < 3; i++)
    k_transpose_w<<<dim3(Kd[i] / 32, HC / 32), 256, 0, stream>>>(W[i], Wt[i], Kd[i]);
  k_cast_f16<<<cdiv(N * 512, 8 * 256), 256, 0, stream>>>(x, axh, N * 512);

  const _Float16* ain = axh;
  int aggGrid = cdiv(N, 4) * NSLICE;
  for (int layer = 0; layer < 3; ++layer) {
    int K = Kd[layer];
    // zero es+ed (contiguous 2*N*16 bytes) for the fused-logits atomics
    hipMemsetAsync(es, 0, (size_t)N * HEADS * 4 * 2, stream);
    k_gemm_mfma<<<dim3(cdiv(N, 128), HC / 128), 256, 0, stream>>>(
        ain, Wt[layer], hsl, AS[layer], AD[layer], es, ed, N, K);
    if (layer < 2) {
      k_aggregate<<<aggGrid, 256, 0, stream>>>(hsl, (const float4*)es, (const float4*)ed, es,
                                               ed, offsets, esd, BI[layer], (float*)nullptr,
                                               acth, N);
    } else {
      k_aggregate<<<aggGrid, 256, 0, stream>>>(hsl, (const float4*)es, (const float4*)ed, es,
                                               ed, offsets, esd, BI[layer], (float*)d_out,
                                               (_Float16*)nullptr, N);
    }
    ain = acth;
  }
}

// Round 22
// 227.826 us; speedup vs baseline: 1.1309x; 1.1309x over previous
//
#include <hip/hip_runtime.h>
#include <hip/hip_fp16.h>
#include <math.h>

#define HEADS 4
#define CH 256
#define HC 1024
#define NSLICE 4
#define NEG_SLOPE 0.2f
#define MAXS 320   // staged CSR slots per block (4 nodes)
#define ASCALE (1.0f / 1024.0f)  // alpha scale: keeps exp() in fp16 range; exact pow2

typedef _Float16 f16x8 __attribute__((ext_vector_type(8)));
typedef _Float16 f16x4 __attribute__((ext_vector_type(4)));
typedef __attribute__((ext_vector_type(4))) float f32x4;

static inline int cdiv(int a, int b) { return (a + b - 1) / b; }

__device__ __forceinline__ __half2 u2h2(unsigned u) {
  union {
    unsigned u;
    __half2 h;
  } x;
  x.u = u;
  return x.h;
}
__device__ __forceinline__ unsigned h22u(__half2 h) {
  union {
    __half2 h;
    unsigned u;
  } x;
  x.h = h;
  return x.u;
}
__device__ __forceinline__ void gload_lds16(const void* g, void* l) {
  __builtin_amdgcn_global_load_lds((const __attribute__((address_space(1))) void*)g,
                                   (__attribute__((address_space(3))) void*)l, 16, 0, 0);
}

// ---------------- CSR build ----------------
__global__ void k_count(const int* __restrict__ ei, int E, int ET, int* __restrict__ cnt) {
  int e = blockIdx.x * blockDim.x + threadIdx.x;
  if (e >= ET) return;
  int d = (e < E) ? ei[E + e] : (e - E);
  atomicAdd(&cnt[d], 1);
}

__global__ __launch_bounds__(1024) void k_scan(const int* __restrict__ counts,
                                               int* __restrict__ offsets, int n) {
  __shared__ int wsum[16];
  __shared__ int carry_s;
  int lane = threadIdx.x & 63, wv = threadIdx.x >> 6;
  if (threadIdx.x == 0) carry_s = 0;
  __syncthreads();
  for (int base = 0; base < n; base += 1024) {
    int i = base + threadIdx.x;
    int orig = (i < n) ? counts[i] : 0;
    int v = orig;
#pragma unroll
    for (int off = 1; off < 64; off <<= 1) {
      int t = __shfl_up(v, off);
      if (lane >= off) v += t;
    }
    if (lane == 63) wsum[wv] = v;
    __syncthreads();
    int carry = carry_s;
    int wpre = 0;
#pragma unroll
    for (int w = 0; w < 16; w++) wpre += (w < wv) ? wsum[w] : 0;
    int incl = v + wpre;
    if (i < n) offsets[i] = carry + incl - orig;
    __syncthreads();
    if (threadIdx.x == 1023) carry_s = carry + incl;
    __syncthreads();
  }
  if (threadIdx.x == 0) offsets[n] = carry_s;
}

__global__ void k_fill(const int* __restrict__ ei, int E, int ET,
                       const int* __restrict__ offsets, int* __restrict__ cursor,
                       int2* __restrict__ esd) {
  int e = blockIdx.x * blockDim.x + threadIdx.x;
  if (e >= ET) return;
  int s = (e < E) ? ei[e] : (e - E);
  int d = (e < E) ? ei[E + e] : (e - E);
  int pos = offsets[d] + atomicAdd(&cursor[d], 1);
  esd[pos] = make_int2(s, d);
}

// ---------------- W transpose + cast to fp16 ----------------
__global__ __launch_bounds__(256) void k_transpose_w(const float* __restrict__ W,
                                                     _Float16* __restrict__ Wt, int K) {
  __shared__ float tile[32][33];
  int tx = threadIdx.x & 31, ty = threadIdx.x >> 5;
  int k0 = blockIdx.x * 32, n0 = blockIdx.y * 32;
#pragma unroll
  for (int r = ty; r < 32; r += 8) tile[r][tx] = W[(size_t)(k0 + r) * HC + n0 + tx];
  __syncthreads();
#pragma unroll
  for (int r = ty; r < 32; r += 8)
    Wt[(size_t)(n0 + r) * K + k0 + tx] = (_Float16)tile[tx][r];
}

// ---------------- cast fp32 -> fp16 ----------------
__global__ void k_cast_f16(const float* __restrict__ in, _Float16* __restrict__ out, int n) {
  int i = (blockIdx.x * blockDim.x + threadIdx.x) * 8;
  if (i >= n) return;
  float4 a = *(const float4*)&in[i];
  float4 b = *(const float4*)&in[i + 4];
  f16x8 o;
  o[0] = (_Float16)a.x;
  o[1] = (_Float16)a.y;
  o[2] = (_Float16)a.z;
  o[3] = (_Float16)a.w;
  o[4] = (_Float16)b.x;
  o[5] = (_Float16)b.y;
  o[6] = (_Float16)b.z;
  o[7] = (_Float16)b.w;
  *(f16x8*)&out[i] = o;
}

// ---------------- fp16 MFMA GEMM, epilogue writes slice-major hsl[c][n][256] ----------
// NSLICE=4: slice c owns head-local channels c*64..+63 of every head.
__global__ __launch_bounds__(256) void k_gemm_mfma(const _Float16* __restrict__ A,
                                                   const _Float16* __restrict__ Bt,
                                                   _Float16* __restrict__ hsl, int M, int K) {
  __shared__ _Float16 sA[2][128 * 32];
  __shared__ _Float16 sB[2][128 * 32];
  int t = threadIdx.x;
  int lane = t & 63, wv = t >> 6;
  int wr = wv >> 1, wc = wv & 1;
  int row0 = blockIdx.x * 128, col0 = blockIdx.y * 128;
  int l15 = lane & 15, l4 = lane >> 4;

  f32x4 acc[4][4] = {};

  auto stage = [&](_Float16* sdst, const _Float16* g, int grow0, int rowmax, int k0) {
#pragma unroll
    for (int q = 0; q < 2; ++q) {
      int r = grow0 + q * 64 + (t >> 2);
      if (r > rowmax) r = rowmax;
      const _Float16* gp = g + (size_t)r * K + k0 + (t & 3) * 8;
      gload_lds16(gp, sdst + q * 2048 + t * 8);
    }
  };

  int KT = K / 32;
  stage(sA[0], A, row0, M - 1, 0);
  stage(sB[0], Bt, col0, HC - 1, 0);
  int cur = 0;
  for (int kt = 0; kt < KT; ++kt) {
    __syncthreads();
    if (kt + 1 < KT) {
      stage(sA[cur ^ 1], A, row0, M - 1, (kt + 1) * 32);
      stage(sB[cur ^ 1], Bt, col0, HC - 1, (kt + 1) * 32);
    }
    f16x8 af[4], bfr[4];
#pragma unroll
    for (int i = 0; i < 4; i++)
      af[i] = *(f16x8*)&sA[cur][(wr * 64 + i * 16 + l15) * 32 + l4 * 8];
#pragma unroll
    for (int j = 0; j < 4; j++)
      bfr[j] = *(f16x8*)&sB[cur][(wc * 64 + j * 16 + l15) * 32 + l4 * 8];
#pragma unroll
    for (int i = 0; i < 4; i++)
#pragma unroll
      for (int j = 0; j < 4; j++)
        acc[i][j] = __builtin_amdgcn_mfma_f32_16x16x32_f16(af[i], bfr[j], acc[i][j], 0, 0, 0);
    cur ^= 1;
  }
#pragma unroll
  for (int i = 0; i < 4; i++) {
#pragma unroll
    for (int j = 0; j < 4; j++) {
      int col = col0 + wc * 64 + j * 16 + l15;
      int head = col >> 8;
      int c = (col >> 6) & 3;
      int jj = col & 63;
      size_t sbase = ((size_t)c * M) * 256 + head * 64 + jj;
#pragma unroll
      for (int r = 0; r < 4; r++) {
        int row = row0 + wr * 64 + i * 16 + l4 * 4 + r;
        if (row < M) hsl[sbase + (size_t)row * 256] = (_Float16)acc[i][j][r];
      }
    }
  }
}

// ---------------- per-node logits from slice-major hsl (NSLICE=4) ----------------
__global__ __launch_bounds__(256) void k_logits(const _Float16* __restrict__ hsl,
                                                const float* __restrict__ as_,
                                                const float* __restrict__ ad_,
                                                float* __restrict__ es, float* __restrict__ ed,
                                                int M) {
  __shared__ float lds_s[4][64];
  __shared__ float lds_d[4][64];
  int n = blockIdx.x;
  int t = threadIdx.x;
  int c = t >> 6, u = t & 63;
  f16x4 hv = *(const f16x4*)&hsl[((size_t)c * M + n) * 256 + u * 4];
  int head = u >> 4;
  int ch = head * 256 + c * 64 + (u & 15) * 4;
  float4 s4 = *(const float4*)&as_[ch];
  float4 d4 = *(const float4*)&ad_[ch];
  float h0 = (float)hv[0], h1 = (float)hv[1], h2 = (float)hv[2], h3 = (float)hv[3];
  float ds = h0 * s4.x + h1 * s4.y + h2 * s4.z + h3 * s4.w;
  float dd = h0 * d4.x + h1 * d4.y + h2 * d4.z + h3 * d4.w;
  lds_s[head][c * 16 + (u & 15)] = ds;
  lds_d[head][c * 16 + (u & 15)] = dd;
  __syncthreads();
  int wv = t >> 6, l = t & 63;
  float vs = lds_s[wv][l];
  float vd = lds_d[wv][l];
#pragma unroll
  for (int off = 32; off; off >>= 1) {
    vs += __shfl_xor(vs, off);
    vd += __shfl_xor(vd, off);
  }
  if (l == 0) {
    es[n * HEADS + wv] = vs;
    ed[n * HEADS + wv] = vd;
  }
}

// ---------------- XCD-sliced aggregation, self-normalizing, alpha computed in staging ----
// Staging loop per block (~68 slots over 256 threads): read esd + es/ed, compute
// leaky+exp+pack inline -> LDS. Denominator from the SAME quantized alphas
// (ASCALE cancels; output is a convex combination of h rows).
__global__ __launch_bounds__(256) void k_aggregate(const _Float16* __restrict__ hsl,
                                                   const float4* __restrict__ es4,
                                                   const float4* __restrict__ ed4,
                                                   const float* __restrict__ es,
                                                   const float* __restrict__ ed,
                                                   const int* __restrict__ offsets,
                                                   const int2* __restrict__ esd,
                                                   const float* __restrict__ bias,
                                                   float* __restrict__ xout,
                                                   _Float16* __restrict__ xout_h, int N) {
  __shared__ uint4 s_ap[MAXS];
  __shared__ int s_src[MAXS];
  int c = blockIdx.x & 3;
  int nb = (blockIdx.x >> 2) * 4;
  int base = offsets[nb];
  int nend = (nb + 4 < N) ? nb + 4 : N;
  int total = offsets[nend] - base;
  int cap = total < MAXS ? total : MAXS;
  for (int idx = threadIdx.x; idx < cap; idx += 256) {
    int2 sd = esd[base + idx];
    float4 a = es4[sd.x], b = ed4[sd.y];
    float v0 = a.x + b.x, v1 = a.y + b.y, v2 = a.z + b.z, v3 = a.w + b.w;
    v0 = v0 > 0.f ? v0 : NEG_SLOPE * v0;
    v1 = v1 > 0.f ? v1 : NEG_SLOPE * v1;
    v2 = v2 > 0.f ? v2 : NEG_SLOPE * v2;
    v3 = v3 > 0.f ? v3 : NEG_SLOPE * v3;
    uint4 ap;
    ap.x = h22u(__float2half2_rn(__expf(v0) * ASCALE));
    ap.y = h22u(__float2half2_rn(__expf(v1) * ASCALE));
    ap.z = h22u(__float2half2_rn(__expf(v2) * ASCALE));
    ap.w = h22u(__float2half2_rn(__expf(v3) * ASCALE));
    s_ap[idx] = ap;
    s_src[idx] = sd.x;
  }
  __syncthreads();
  int n = nb + (threadIdx.x >> 6);
  if (n >= N) return;
  int lane = threadIdx.x & 63;
  int g = lane >> 5;   // edge subgroup (2)
  int q = lane & 31;   // 16B segment of the 512B slice row
  int hq = q >> 3;     // head of this segment
  const _Float16* sl = hsl + (size_t)c * N * 256;
  const __half2* aph = (const __half2*)s_ap;
  __half2 z2 = __float2half2_rn(0.f);
  __half2 acc2[4] = {z2, z2, z2, z2};
  __half2 sum2 = z2;
  int k0 = offsets[n], k1 = offsets[n + 1];
  int r = k0 - base + g;
  int rend = k1 - base;
  if (total <= MAXS) {
    for (; r + 2 < rend; r += 4) {
      int sA = s_src[r], sB = s_src[r + 2];
      __half2 aA = aph[r * 4 + hq];
      __half2 aB = aph[(r + 2) * 4 + hq];
      uint4 hA = *(const uint4*)&sl[(size_t)sA * 256 + q * 8];
      uint4 hB = *(const uint4*)&sl[(size_t)sB * 256 + q * 8];
      sum2 = __hadd2(sum2, __hadd2(aA, aB));
      acc2[0] = __hfma2(aA, u2h2(hA.x), acc2[0]);
      acc2[1] = __hfma2(aA, u2h2(hA.y), acc2[1]);
      acc2[2] = __hfma2(aA, u2h2(hA.z), acc2[2]);
      acc2[3] = __hfma2(aA, u2h2(hA.w), acc2[3]);
      acc2[0] = __hfma2(aB, u2h2(hB.x), acc2[0]);
      acc2[1] = __hfma2(aB, u2h2(hB.y), acc2[1]);
      acc2[2] = __hfma2(aB, u2h2(hB.z), acc2[2]);
      acc2[3] = __hfma2(aB, u2h2(hB.w), acc2[3]);
    }
    if (r < rend) {
      int sA = s_src[r];
      __half2 aA = aph[r * 4 + hq];
      uint4 hA = *(const uint4*)&sl[(size_t)sA * 256 + q * 8];
      sum2 = __hadd2(sum2, aA);
      acc2[0] = __hfma2(aA, u2h2(hA.x), acc2[0]);
      acc2[1] = __hfma2(aA, u2h2(hA.y), acc2[1]);
      acc2[2] = __hfma2(aA, u2h2(hA.z), acc2[2]);
      acc2[3] = __hfma2(aA, u2h2(hA.w), acc2[3]);
    }
  } else {
    // overflow fallback (essentially never): compute alpha inline from es/ed
    for (; r < rend; r += 2) {
      int2 sd = esd[base + r];
      float v = es[sd.x * 4 + hq] + ed[sd.y * 4 + hq];
      v = v > 0.f ? v : NEG_SLOPE * v;
      __half2 aA = __float2half2_rn(__expf(v) * ASCALE);
      uint4 hA = *(const uint4*)&sl[(size_t)sd.x * 256 + q * 8];
      sum2 = __hadd2(sum2, aA);
      acc2[0] = __hfma2(aA, u2h2(hA.x), acc2[0]);
      acc2[1] = __hfma2(aA, u2h2(hA.y), acc2[1]);
      acc2[2] = __hfma2(aA, u2h2(hA.z), acc2[2]);
      acc2[3] = __hfma2(aA, u2h2(hA.w), acc2[3]);
    }
  }
  float sa = __low2float(sum2);
  sa += __shfl_xor(sa, 32);  // combine the 2 edge groups (per-head total)
  float ia = 0.25f / (sa + 1e-20f);
  float acc[8];
#pragma unroll
  for (int j = 0; j < 4; j++) {
    acc[2 * j] = __low2float(acc2[j]) * ia;
    acc[2 * j + 1] = __high2float(acc2[j]) * ia;
  }
#pragma unroll
  for (int j = 0; j < 8; j++) {
    float v = acc[j];
    v += __shfl_xor(v, 8);   // heads bit0
    v += __shfl_xor(v, 16);  // heads bit1
    v += __shfl_xor(v, 32);  // edge groups
    acc[j] = v;
  }
  if (lane < 8) {
    int oc = c * 64 + lane * 8;
    if (xout) {
      float4 o0 = make_float4(acc[0] + bias[oc + 0], acc[1] + bias[oc + 1],
                              acc[2] + bias[oc + 2], acc[3] + bias[oc + 3]);
      float4 o1 = make_float4(acc[4] + bias[oc + 4], acc[5] + bias[oc + 5],
                              acc[6] + bias[oc + 6], acc[7] + bias[oc + 7]);
      *(float4*)&xout[(size_t)n * CH + oc] = o0;
      *(float4*)&xout[(size_t)n * CH + oc + 4] = o1;
    }
    if (xout_h) {
      f16x8 o;
#pragma unroll
      for (int j = 0; j < 8; j++) o[j] = (_Float16)(acc[j] + bias[oc + j]);
      *(f16x8*)&xout_h[(size_t)n * CH + oc] = o;
    }
  }
}

extern "C" void kernel_launch(void* const* d_in, const int* in_sizes, int n_in,
                              void* d_out, int out_size, void* d_ws, size_t ws_size,
                              hipStream_t stream) {
  const float* x = (const float*)d_in[0];
  const int* ei = (const int*)d_in[1];
  const float* W[3] = {(const float*)d_in[2], (const float*)d_in[6], (const float*)d_in[10]};
  const float* AS[3] = {(const float*)d_in[3], (const float*)d_in[7], (const float*)d_in[11]};
  const float* AD[3] = {(const float*)d_in[4], (const float*)d_in[8], (const float*)d_in[12]};
  const float* BI[3] = {(const float*)d_in[5], (const float*)d_in[9], (const float*)d_in[13]};
  const int N = in_sizes[0] / 512;
  const int E = in_sizes[1] / 2;
  const int ET = E + N;
  const int Kd[3] = {512, 256, 256};

  char* p = (char*)d_ws;
  auto alloc = [&](size_t bytes) {
    char* r = p;
    p += (bytes + 255) & ~(size_t)255;
    return (void*)r;
  };
  _Float16* hsl = (_Float16*)alloc((size_t)NSLICE * N * 256 * 2);
  _Float16* axh = (_Float16*)alloc((size_t)N * 512 * 2);
  _Float16* acth = (_Float16*)alloc((size_t)N * CH * 2);
  _Float16* Wt[3];
  for (int i = 0; i < 3; i++) Wt[i] = (_Float16*)alloc((size_t)HC * Kd[i] * 2);
  float* es = (float*)alloc((size_t)N * HEADS * 4);
  float* ed = (float*)alloc((size_t)N * HEADS * 4);
  int* offsets = (int*)alloc((size_t)(N + 1) * 4);
  int* cursor = (int*)alloc((size_t)N * 4);
  int2* esd = (int2*)alloc((size_t)ET * 8);

  // ---- CSR build (shared by all 3 layers) ----
  hipMemsetAsync(cursor, 0, (size_t)N * 4, stream);
  k_count<<<cdiv(ET, 256), 256, 0, stream>>>(ei, E, ET, cursor);
  k_scan<<<1, 1024, 0, stream>>>(cursor, offsets, N);
  hipMemsetAsync(cursor, 0, (size_t)N * 4, stream);
  k_fill<<<cdiv(ET, 256), 256, 0, stream>>>(ei, E, ET, offsets, cursor, esd);

  // ---- weight transpose+cast, input cast ----
  for (int i = 0; i < 3; i++)
    k_transpose_w<<<dim3(Kd[i] / 32, HC / 32), 256, 0, stream>>>(W[i], Wt[i], Kd[i]);
  k_cast_f16<<<cdiv(N * 512, 8 * 256), 256, 0, stream>>>(x, axh, N * 512);

  const _Float16* ain = axh;
  int aggGrid = cdiv(N, 4) * NSLICE;
  for (int layer = 0; layer < 3; ++layer) {
    int K = Kd[layer];
    k_gemm_mfma<<<dim3(cdiv(N, 128), HC / 128), 256, 0, stream>>>(ain, Wt[layer], hsl, N, K);
    k_logits<<<N, 256, 0, stream>>>(hsl, AS[layer], AD[layer], es, ed, N);
    if (layer < 2) {
      k_aggregate<<<aggGrid, 256, 0, stream>>>(hsl, (const float4*)es, (const float4*)ed, es,
                                               ed, offsets, esd, BI[layer], (float*)nullptr,
                                               acth, N);
    } else {
      k_aggregate<<<aggGrid, 256, 0, stream>>>(hsl, (const float4*)es, (const float4*)ed, es,
                                               ed, offsets, esd, BI[layer], (float*)d_out,
                                               (_Float16*)nullptr, N);
    }
    ain = acth;
  }
}